// Round 1
// baseline (279.670 us; speedup 1.0000x reference)
//
#include <hip/hip_runtime.h>
#include <cmath>

typedef __attribute__((ext_vector_type(8))) short short8;
typedef __attribute__((ext_vector_type(4))) float f32x4;

static __device__ __forceinline__ unsigned short f2bf(float x) {
  unsigned int u = __float_as_uint(x);
  unsigned int r = (u + 0x7FFFu + ((u >> 16) & 1u)) >> 16;
  return (unsigned short)r;
}
static __device__ __forceinline__ float bf2f(unsigned short u) {
  return __uint_as_float(((unsigned int)u) << 16);
}

// ---------------- cond = w @ affine_w.T + affine_b ; ssum += cond^2 ----------
__global__ __launch_bounds__(256) void k_cond(const float* __restrict__ w,
    const float* __restrict__ aw, const float* __restrict__ ab,
    float* __restrict__ cond, float* __restrict__ ssum) {
  int t = blockIdx.x * 256 + threadIdx.x;   // 8192
  int b = t >> 9, i = t & 511;
  const float4* wr = (const float4*)(w + b * 512);
  const float4* ar = (const float4*)(aw + i * 512);
  float acc = 0.f;
  for (int j = 0; j < 128; ++j) {
    float4 a = ar[j], v = wr[j];
    acc += a.x * v.x + a.y * v.y + a.z * v.z + a.w * v.w;
  }
  float c = acc + ab[i];
  cond[t] = c;
  float s = c * c;
  #pragma unroll
  for (int off = 32; off >= 1; off >>= 1) s += __shfl_down(s, off);
  if ((threadIdx.x & 63) == 0) atomicAdd(ssum, s);
}

// ------- per-o weight RMS, W2T[i][o] = sum_k w^2, bf16 MFMA-fragment pack ----
__global__ __launch_bounds__(256) void k_wprep(const float* __restrict__ cw,
    float* __restrict__ W2T, float* __restrict__ rinv,
    unsigned short* __restrict__ wpack) {
  int o = blockIdx.x, t = threadIdx.x;
  const float* row = cw + o * 1536;
  __shared__ float red[4];
  float local = 0.f;
  for (int r = 0; r < 2; ++r) {
    int i = t + 256 * r;
    float a = row[3 * i], b = row[3 * i + 1], c = row[3 * i + 2];
    float w2 = a * a + b * b + c * c;
    W2T[i * 512 + o] = w2;
    local += w2;
    int chunk = i >> 5;
    int laneo = (((i >> 3) & 3) << 4) + (o & 15);
    int e = i & 7;
    int base = (chunk * 32 + (o >> 4)) * 512 + laneo * 8 + e;  // k=0
    wpack[base] = f2bf(a);
    wpack[base + 16 * 32 * 512] = f2bf(b);        // k=1
    wpack[base + 2 * 16 * 32 * 512] = f2bf(c);    // k=2
  }
  #pragma unroll
  for (int off = 32; off >= 1; off >>= 1) local += __shfl_down(local, off);
  if ((t & 63) == 0) red[t >> 6] = local;
  __syncthreads();
  if (t == 0) {
    float m = red[0] + red[1] + red[2] + red[3];
    rinv[o] = rsqrtf(m * (1.f / 1536.f));
  }
}

// --------- coef[b,o] = r_o * rsqrt(r_o^2 * sum_i W2[o,i]*s[b,i]^2 + 1e-8) ----
__global__ __launch_bounds__(256) void k_dcoef(const float* __restrict__ W2T,
    const float* __restrict__ cond, const float* __restrict__ rinv,
    const float* __restrict__ ssum, float* __restrict__ coef) {
  int t = blockIdx.x * 256 + threadIdx.x;   // 8192
  int b = t >> 9, o = t & 511;
  float inv_ms = 8192.f / ssum[0];
  const float* cb = cond + b * 512;
  float acc = 0.f;
  for (int i = 0; i < 512; ++i) {
    float s = cb[i];
    acc += W2T[i * 512 + o] * (s * s);
  }
  float ro = rinv[o];
  coef[t] = ro * rsqrtf(ro * ro * acc * inv_ms + 1e-8f);
}

// ------------- xsT[b][l][i] = bf16(x[b][i][l] * s_eff[b][i]) -----------------
__global__ __launch_bounds__(256) void k_xprep(const float* __restrict__ x,
    const float* __restrict__ cond, const float* __restrict__ ssum,
    const float* __restrict__ nrm, unsigned short* __restrict__ xsT) {
  int lb = blockIdx.x, ib = blockIdx.y, b = blockIdx.z;
  int t = threadIdx.x;
  int l0 = lb * 64, i0 = ib * 64;
  __shared__ float tile[64][65];
  float sc = rsqrtf(ssum[0] * (1.f / 8192.f)) * rsqrtf(nrm[0]);
  int tr = t >> 4, tc = (t & 15) * 4;
  #pragma unroll
  for (int rr = 0; rr < 4; ++rr) {
    int il = rr * 16 + tr;
    float se = cond[b * 512 + i0 + il] * sc;
    float4 v = *(const float4*)(x + (b * 512 + i0 + il) * 2048 + l0 + tc);
    tile[il][tc + 0] = v.x * se;
    tile[il][tc + 1] = v.y * se;
    tile[il][tc + 2] = v.z * se;
    tile[il][tc + 3] = v.w * se;
  }
  __syncthreads();
  int lr = t >> 3, ic = (t & 7) * 8;
  #pragma unroll
  for (int rr = 0; rr < 2; ++rr) {
    int ll = rr * 32 + lr;
    uint4 u;
    unsigned int pk[4];
    #pragma unroll
    for (int j = 0; j < 4; ++j) {
      unsigned short lo = f2bf(tile[ic + 2 * j][ll]);
      unsigned short hi = f2bf(tile[ic + 2 * j + 1][ll]);
      pk[j] = (unsigned int)lo | ((unsigned int)hi << 16);
    }
    u.x = pk[0]; u.y = pk[1]; u.z = pk[2]; u.w = pk[3];
    *(uint4*)(xsT + (b * 2048 + l0 + ll) * 512 + i0 + ic) = u;
  }
}

// ----------------- main: y[b,o,l] = conv(xs, W)*coef + bias ------------------
// block tile: 128 o x 128 l, K=512 (i) in 16 chunks of 32; conv taps k=0..2 as
// column-shifted reads of the LDS x-tile. 4 waves (2x2), wave tile 64x64.
__global__ __launch_bounds__(256) void k_main(const unsigned short* __restrict__ xsT,
    const unsigned short* __restrict__ wpack, const float* __restrict__ coef,
    const float* __restrict__ convb, unsigned short* __restrict__ y) {
  int lb = blockIdx.x, ob = blockIdx.y, b = blockIdx.z;
  int t = threadIdx.x, lane = t & 63, wave = t >> 6;
  int wr = wave >> 1, wc = wave & 1;
  int l0 = lb * 128, o0 = ob * 128;
  __shared__ unsigned short Al[3 * 8 * 512];   // 24576 B, [k][og][lane*8]
  __shared__ unsigned short Bl[4160];          // 8320 B, swizzled [col][i]
  f32x4 acc[4][4];
  f32x4 z4 = {0.f, 0.f, 0.f, 0.f};
  #pragma unroll
  for (int i = 0; i < 4; ++i)
    #pragma unroll
    for (int j = 0; j < 4; ++j) acc[i][j] = z4;

  for (int c = 0; c < 16; ++c) {
    // stage A (weights, already fragment-ordered in global)
    #pragma unroll
    for (int j = 0; j < 6; ++j) {
      int f = j * 256 + t;          // 16B units, 1536 total
      int r = f >> 6, ln = f & 63;  // r = k*8+og
      int k = r >> 3, og = r & 7;
      uint4 v = *(const uint4*)(wpack + ((k * 16 + c) * 32 + ob * 8 + og) * 512 + ln * 8);
      *(uint4*)(&Al[r * 512 + ln * 8]) = v;
    }
    // stage B (x tile, transposed-in-global, XOR-swizzled in LDS)
    #pragma unroll
    for (int rep = 0; rep < 3; ++rep) {
      int f = rep * 256 + t;
      if (f < 520) {                 // 130 cols x 4 sixteen-byte pieces
        int col = f >> 2, q = f & 3;
        int gcol = l0 - 1 + col;
        uint4 v; v.x = 0u; v.y = 0u; v.z = 0u; v.w = 0u;
        if (gcol >= 0 && gcol < 2048)
          v = *(const uint4*)(xsT + (b * 2048 + gcol) * 512 + c * 32 + q * 8);
        int byte = (col * 64 + q * 16) ^ ((col & 7) << 4);
        *(uint4*)((char*)Bl + byte) = v;
      }
    }
    __syncthreads();
    #pragma unroll
    for (int k = 0; k < 3; ++k) {
      short8 af[4], bfr[4];
      #pragma unroll
      for (int rg = 0; rg < 4; ++rg)
        af[rg] = *(const short8*)(&Al[(k * 8 + wr * 4 + rg) * 512 + lane * 8]);
      #pragma unroll
      for (int cg = 0; cg < 4; ++cg) {
        int col = wc * 64 + cg * 16 + (lane & 15) + k;
        int byte = (col * 64 + ((lane >> 4) << 4)) ^ ((col & 7) << 4);
        bfr[cg] = *(const short8*)((const char*)Bl + byte);
      }
      #pragma unroll
      for (int rg = 0; rg < 4; ++rg)
        #pragma unroll
        for (int cg = 0; cg < 4; ++cg)
          acc[rg][cg] = __builtin_amdgcn_mfma_f32_16x16x32_bf16(af[rg], bfr[cg], acc[rg][cg], 0, 0, 0);
    }
    __syncthreads();
  }
  // epilogue: *coef + bias, store bf16 y
  int lq = lane >> 4, lrr = lane & 15;
  #pragma unroll
  for (int rg = 0; rg < 4; ++rg) {
    int o2 = o0 + wr * 64 + rg * 16 + lq * 4;
    float c0 = coef[b * 512 + o2 + 0], c1 = coef[b * 512 + o2 + 1];
    float c2 = coef[b * 512 + o2 + 2], c3 = coef[b * 512 + o2 + 3];
    float b0 = convb[o2 + 0], b1 = convb[o2 + 1];
    float b2 = convb[o2 + 2], b3 = convb[o2 + 3];
    #pragma unroll
    for (int cg = 0; cg < 4; ++cg) {
      int l = l0 + wc * 64 + cg * 16 + lrr;
      y[(b * 512 + o2 + 0) * 2048 + l] = f2bf(acc[rg][cg][0] * c0 + b0);
      y[(b * 512 + o2 + 1) * 2048 + l] = f2bf(acc[rg][cg][1] * c1 + b1);
      y[(b * 512 + o2 + 2) * 2048 + l] = f2bf(acc[rg][cg][2] * c2 + b2);
      y[(b * 512 + o2 + 3) * 2048 + l] = f2bf(acc[rg][cg][3] * c3 + b3);
    }
  }
}

// ------- halfband up-LPF -> lrelu*sqrt2 -> halfband down-LPF, decimated ------
struct Taps { float f[8]; };

__global__ __launch_bounds__(256) void k_filter(const unsigned short* __restrict__ y,
    float* __restrict__ out, Taps tp) {
  int ch = blockIdx.x;          // b*512 + c
  int l0 = blockIdx.y * 1024;
  int t = threadIdx.x;
  __shared__ float ys[1040];    // y[l0-7 .. l0+1031)
  __shared__ float ao[1032];    // a_odd[l0-4 .. l0+1028)
  const unsigned short* yc = y + ch * 2048;
  for (int j = t; j < 1038; j += 256) {
    int pos = l0 - 7 + j;
    ys[j] = (pos >= 0 && pos < 2048) ? bf2f(yc[pos]) : 0.f;
  }
  __syncthreads();
  const float s2 = 1.41421356237309515f;
  for (int j = t; j < 1032; j += 256) {
    int t4 = l0 - 4 + j;
    float u = 0.f;
    #pragma unroll
    for (int p = 0; p < 8; ++p) u += tp.f[p] * ys[j + p];
    float a = (u >= 0.f ? u : 0.1f * u) * s2;
    ao[j] = (t4 >= 0 && t4 < 2048) ? a : 0.f;
  }
  __syncthreads();
  const float ce = 0.35355339059327379f;   // 0.5 * sqrt2 * 0.5
  int m0 = t * 4;
  float4 r;
  float rv[4];
  #pragma unroll
  for (int jj = 0; jj < 4; ++jj) {
    int m = m0 + jj;
    float yv = ys[m + 7];
    float e = ce * (yv >= 0.f ? yv : 0.1f * yv);
    float s = 0.f;
    #pragma unroll
    for (int q = 0; q < 8; ++q) s += tp.f[q] * ao[m + q];
    rv[jj] = e + s;
  }
  r.x = rv[0]; r.y = rv[1]; r.z = rv[2]; r.w = rv[3];
  *(float4*)(out + ch * 2048 + l0 + m0) = r;
}

// ------------------------------- host side -----------------------------------
static double bessel_i0(double x) {
  double s = 1.0, term = 1.0;
  for (int m = 1; m < 30; ++m) {
    double h = x * 0.5 / (double)m;
    term *= h * h;
    s += term;
  }
  return s;
}

extern "C" void kernel_launch(void* const* d_in, const int* in_sizes, int n_in,
                              void* d_out, int out_size, void* d_ws, size_t ws_size,
                              hipStream_t stream) {
  (void)in_sizes; (void)n_in; (void)out_size; (void)ws_size;
  const float* x  = (const float*)d_in[0];
  const float* w  = (const float*)d_in[1];
  const float* aw = (const float*)d_in[2];
  const float* ab = (const float*)d_in[3];
  const float* cw = (const float*)d_in[4];
  const float* cb = (const float*)d_in[5];
  const float* ne = (const float*)d_in[6];
  float* out = (float*)d_out;
  char* ws = (char*)d_ws;

  float* ssum = (float*)(ws + 0);
  float* cond = (float*)(ws + 256);
  float* rinv = (float*)(ws + 33024);
  float* coef = (float*)(ws + 35072);
  float* W2T  = (float*)(ws + 67840);
  unsigned short* wpack = (unsigned short*)(ws + 1116416);
  unsigned short* xsT   = (unsigned short*)(ws + 2689280);
  unsigned short* yb    = (unsigned short*)(ws + 36243712);

  hipMemsetAsync(ssum, 0, 4, stream);
  k_cond<<<32, 256, 0, stream>>>(w, aw, ab, cond, ssum);
  k_wprep<<<512, 256, 0, stream>>>(cw, W2T, rinv, wpack);
  k_dcoef<<<32, 256, 0, stream>>>(W2T, cond, rinv, ssum, coef);
  k_xprep<<<dim3(32, 8, 16), 256, 0, stream>>>(x, cond, ssum, ne, xsT);
  k_main<<<dim3(16, 4, 16), 256, 0, stream>>>(xsT, wpack, coef, cb, yb);

  Taps tp;
  {
    double beta = 2.5;
    double i0b = bessel_i0(beta);
    for (int p = 0; p < 8; ++p) {
      int j = 2 * p + 1;          // odd tap index in 0..16
      int n = j - 8;              // -7..7 odd
      double f = sin(0.5 * M_PI * (double)n) / (M_PI * (double)n + 1e-8);
      double rr = (double)(j - 8) / 8.0;
      double win = bessel_i0(beta * sqrt(1.0 - rr * rr)) / i0b;
      tp.f[p] = (float)(win * f);
    }
  }
  k_filter<<<dim3(8192, 2), 256, 0, stream>>>(yb, out, tp);
}

// Round 2
// 208.408 us; speedup vs baseline: 1.3419x; 1.3419x over previous
//
#include <hip/hip_runtime.h>
#include <cmath>

typedef __attribute__((ext_vector_type(8))) short short8;
typedef __attribute__((ext_vector_type(4))) float f32x4;

static __device__ __forceinline__ unsigned short f2bf(float x) {
  unsigned int u = __float_as_uint(x);
  unsigned int r = (u + 0x7FFFu + ((u >> 16) & 1u)) >> 16;
  return (unsigned short)r;
}
static __device__ __forceinline__ float bf2f(unsigned short u) {
  return __uint_as_float(((unsigned int)u) << 16);
}
static __device__ __forceinline__ void glds16(const unsigned short* g, unsigned short* l) {
  __builtin_amdgcn_global_load_lds((const __attribute__((address_space(1))) unsigned int*)(g),
                                   (__attribute__((address_space(3))) unsigned int*)(l), 16, 0, 0);
}

// ---------------- cond = w @ affine_w.T + affine_b ; ssum += cond^2 ----------
__global__ __launch_bounds__(256) void k_cond(const float* __restrict__ w,
    const float* __restrict__ aw, const float* __restrict__ ab,
    float* __restrict__ cond, float* __restrict__ ssum) {
  int t = threadIdx.x;
  int outp = blockIdx.x * 64 + (t >> 2);   // 8192 outputs
  int sub = t & 3;
  int b = outp >> 9, i = outp & 511;
  const float4* wr = (const float4*)(w + b * 512);
  const float4* ar = (const float4*)(aw + i * 512);
  float acc = 0.f;
  #pragma unroll
  for (int jj = 0; jj < 32; ++jj) {
    int j = sub + jj * 4;
    float4 a = ar[j], v = wr[j];
    acc += a.x * v.x + a.y * v.y + a.z * v.z + a.w * v.w;
  }
  acc += __shfl_xor(acc, 1);
  acc += __shfl_xor(acc, 2);
  float s = 0.f;
  if (sub == 0) {
    float c = acc + ab[i];
    cond[outp] = c;
    s = c * c;
  }
  #pragma unroll
  for (int off = 4; off <= 32; off <<= 1) s += __shfl_xor(s, off);
  if ((t & 63) == 0) atomicAdd(ssum, s);
}

// ------- per-o weight RMS, W2[o][i] = sum_k w^2, bf16 MFMA-fragment pack -----
__global__ __launch_bounds__(256) void k_wprep(const float* __restrict__ cw,
    float* __restrict__ W2, float* __restrict__ rinv,
    unsigned short* __restrict__ wpack) {
  int o = blockIdx.x, t = threadIdx.x;
  const float* row = cw + o * 1536;
  __shared__ float red[4];
  float local = 0.f;
  for (int r = 0; r < 2; ++r) {
    int i = t + 256 * r;
    float a = row[3 * i], b = row[3 * i + 1], c = row[3 * i + 2];
    float w2 = a * a + b * b + c * c;
    W2[o * 512 + i] = w2;
    local += w2;
    int chunk = i >> 5;
    int laneo = (((i >> 3) & 3) << 4) + (o & 15);
    int e = i & 7;
    int base = (chunk * 32 + (o >> 4)) * 512 + laneo * 8 + e;  // k=0
    wpack[base] = f2bf(a);
    wpack[base + 16 * 32 * 512] = f2bf(b);        // k=1
    wpack[base + 2 * 16 * 32 * 512] = f2bf(c);    // k=2
  }
  #pragma unroll
  for (int off = 32; off >= 1; off >>= 1) local += __shfl_down(local, off);
  if ((t & 63) == 0) red[t >> 6] = local;
  __syncthreads();
  if (t == 0) {
    float m = red[0] + red[1] + red[2] + red[3];
    rinv[o] = rsqrtf(m * (1.f / 1536.f));
  }
}

// --------- coef[b,o] = r_o * rsqrt(r_o^2 * sum_i W2[o,i]*s[b,i]^2 + 1e-8) ----
__global__ __launch_bounds__(256) void k_dcoef(const float* __restrict__ W2,
    const float* __restrict__ cond, const float* __restrict__ rinv,
    const float* __restrict__ ssum, float* __restrict__ coef) {
  int og = blockIdx.x, b = blockIdx.y;
  int t = threadIdx.x;
  int o = og * 32 + (t >> 3);
  int il = t & 7;
  __shared__ float s2[512];
  float c0 = cond[b * 512 + t];
  float c1 = cond[b * 512 + t + 256];
  s2[t] = c0 * c0;
  s2[t + 256] = c1 * c1;
  __syncthreads();
  float acc = 0.f;
  #pragma unroll
  for (int jj = 0; jj < 16; ++jj) {
    int i = jj * 32 + il * 4;
    float4 wv = *(const float4*)(W2 + o * 512 + i);
    acc += wv.x * s2[i] + wv.y * s2[i + 1] + wv.z * s2[i + 2] + wv.w * s2[i + 3];
  }
  acc += __shfl_xor(acc, 1);
  acc += __shfl_xor(acc, 2);
  acc += __shfl_xor(acc, 4);
  if (il == 0) {
    float inv_ms = 8192.f / ssum[0];
    float ro = rinv[o];
    coef[b * 512 + o] = ro * rsqrtf(ro * ro * acc * inv_ms + 1e-8f);
  }
}

// ------------- xsT[b][1+l][i] = bf16(x[b][i][l] * s_eff[b][i]) ---------------
// stride 2050 cols per b; col 0 = guard (l=-1), col 2049 = guard (l=2048)
__global__ __launch_bounds__(256) void k_xprep(const float* __restrict__ x,
    const float* __restrict__ cond, const float* __restrict__ ssum,
    const float* __restrict__ nrm, unsigned short* __restrict__ xsT) {
  int lb = blockIdx.x, ib = blockIdx.y, b = blockIdx.z;
  int t = threadIdx.x;
  int l0 = lb * 64, i0 = ib * 64;
  __shared__ float tile[64][65];
  float sc = rsqrtf(ssum[0] * (1.f / 8192.f)) * rsqrtf(nrm[0]);
  int tr = t >> 4, tc = (t & 15) * 4;
  #pragma unroll
  for (int rr = 0; rr < 4; ++rr) {
    int il = rr * 16 + tr;
    float se = cond[b * 512 + i0 + il] * sc;
    float4 v = *(const float4*)(x + ((size_t)b * 512 + i0 + il) * 2048 + l0 + tc);
    tile[il][tc + 0] = v.x * se;
    tile[il][tc + 1] = v.y * se;
    tile[il][tc + 2] = v.z * se;
    tile[il][tc + 3] = v.w * se;
  }
  __syncthreads();
  int lr = t >> 3, ic = (t & 7) * 8;
  #pragma unroll
  for (int rr = 0; rr < 2; ++rr) {
    int ll = rr * 32 + lr;
    uint4 u;
    unsigned int pk[4];
    #pragma unroll
    for (int j = 0; j < 4; ++j) {
      unsigned short lo = f2bf(tile[ic + 2 * j][ll]);
      unsigned short hi = f2bf(tile[ic + 2 * j + 1][ll]);
      pk[j] = (unsigned int)lo | ((unsigned int)hi << 16);
    }
    u.x = pk[0]; u.y = pk[1]; u.z = pk[2]; u.w = pk[3];
    *(uint4*)(xsT + ((size_t)b * 2050 + 1 + l0 + ll) * 512 + i0 + ic) = u;
  }
  // guard columns (zero), written once per (b, i-range)
  if (lb == 0 && t < 8) {
    uint4 z; z.x = 0; z.y = 0; z.z = 0; z.w = 0;
    *(uint4*)(xsT + ((size_t)b * 2050) * 512 + i0 + t * 8) = z;
  }
  if (lb == 31 && t < 8) {
    uint4 z; z.x = 0; z.y = 0; z.z = 0; z.w = 0;
    *(uint4*)(xsT + ((size_t)b * 2050 + 2049) * 512 + i0 + t * 8) = z;
  }
}

// ----------------- main: y[b,o,l] = conv(xs, W)*coef + bias ------------------
// 128o x 128l tile, 4 waves (2x2). A (weights) in regs double-buffered;
// B (x) double-buffered in LDS via global_load_lds, XOR-swizzled via
// pre-swizzled global source. K = 512 i in 16 chunks of 32, 3 taps as
// col-shifted LDS reads. y stored bf16 into d_out rows (stride 4096 u16).
#define STAGE_B(buf, c) { \
  _Pragma("unroll") for (int j_ = 0; j_ < 3; ++j_) { \
    int f_ = j_ * 256 + t; \
    if (f_ < 520) { \
      int col_ = ((f_ >> 3) << 1) | (((f_ >> 2) ^ (f_ >> 4)) & 1); \
      int q_ = ((f_ ^ (f_ >> 2) ^ (f_ >> 4)) & 1) | ((((f_ >> 1) ^ (f_ >> 3)) & 1) << 1); \
      const unsigned short* src_ = xsT + ((size_t)b * 2050 + l0 + col_) * 512 + (c) * 32 + q_ * 8; \
      glds16(src_, &Bl[buf][(f_ & ~63) * 8]); \
    } \
  } }

#define LOAD_A(Ar, c) { \
  _Pragma("unroll") for (int k_ = 0; k_ < 3; ++k_) \
  _Pragma("unroll") for (int rg_ = 0; rg_ < 4; ++rg_) \
    Ar[k_ * 4 + rg_] = *(const short8*)(wpack + ((size_t)((k_ * 16 + (c)) * 32 + ob * 8 + wr * 4 + rg_)) * 512 + lane * 8); }

#define MFMA_STEP(Ar, buf) { \
  _Pragma("unroll") for (int k_ = 0; k_ < 3; ++k_) { \
    short8 bfr_[4]; \
    _Pragma("unroll") for (int cg_ = 0; cg_ < 4; ++cg_) { \
      int col_ = wc * 64 + cg_ * 16 + (lane & 15) + k_; \
      int byte_ = (col_ * 64 + ((lane >> 4) << 4)) ^ ((col_ & 7) << 4); \
      bfr_[cg_] = *(const short8*)((const char*)Bl[buf] + byte_); \
    } \
    _Pragma("unroll") for (int rg_ = 0; rg_ < 4; ++rg_) \
      _Pragma("unroll") for (int cg_ = 0; cg_ < 4; ++cg_) \
        acc[rg_][cg_] = __builtin_amdgcn_mfma_f32_16x16x32_bf16(Ar[k_ * 4 + rg_], bfr_[cg_], acc[rg_][cg_], 0, 0, 0); \
  } }

__global__ __launch_bounds__(256, 2) void k_main(const unsigned short* __restrict__ xsT,
    const unsigned short* __restrict__ wpack, const float* __restrict__ coef,
    const float* __restrict__ convb, unsigned short* __restrict__ y) {
  int lb = blockIdx.x, ob = blockIdx.y, b = blockIdx.z;
  int t = threadIdx.x, lane = t & 63, wave = t >> 6;
  int wr = wave >> 1, wc = wave & 1;
  int l0 = lb * 128, o0 = ob * 128;
  __shared__ __align__(16) unsigned short Bl[2][4160];   // 2 x 8320 B, swizzled
  f32x4 acc[4][4];
  f32x4 z4 = {0.f, 0.f, 0.f, 0.f};
  #pragma unroll
  for (int i = 0; i < 4; ++i)
    #pragma unroll
    for (int j = 0; j < 4; ++j) acc[i][j] = z4;

  short8 A0[12], A1[12];
  LOAD_A(A0, 0);
  STAGE_B(0, 0);
  __syncthreads();
  for (int cc = 0; cc < 16; cc += 2) {
    if (cc + 1 < 16) { STAGE_B(1, cc + 1); LOAD_A(A1, cc + 1); }
    MFMA_STEP(A0, 0);
    __syncthreads();
    if (cc + 2 < 16) { STAGE_B(0, cc + 2); LOAD_A(A0, cc + 2); }
    MFMA_STEP(A1, 1);
    __syncthreads();
  }
  // epilogue: *coef + bias, store bf16 y into d_out rows (u16 stride 4096)
  int lq = lane >> 4, lrr = lane & 15;
  #pragma unroll
  for (int rg = 0; rg < 4; ++rg) {
    int o2 = o0 + wr * 64 + rg * 16 + lq * 4;
    float c0 = coef[b * 512 + o2 + 0], c1 = coef[b * 512 + o2 + 1];
    float c2 = coef[b * 512 + o2 + 2], c3 = coef[b * 512 + o2 + 3];
    float b0 = convb[o2 + 0], b1 = convb[o2 + 1];
    float b2 = convb[o2 + 2], b3 = convb[o2 + 3];
    #pragma unroll
    for (int cg = 0; cg < 4; ++cg) {
      int l = l0 + wc * 64 + cg * 16 + lrr;
      y[((size_t)b * 512 + o2 + 0) * 4096 + l] = f2bf(acc[rg][cg][0] * c0 + b0);
      y[((size_t)b * 512 + o2 + 1) * 4096 + l] = f2bf(acc[rg][cg][1] * c1 + b1);
      y[((size_t)b * 512 + o2 + 2) * 4096 + l] = f2bf(acc[rg][cg][2] * c2 + b2);
      y[((size_t)b * 512 + o2 + 3) * 4096 + l] = f2bf(acc[rg][cg][3] * c3 + b3);
    }
  }
}

// ------- halfband up-LPF -> lrelu*sqrt2 -> halfband down-LPF, decimated ------
// one block per channel; y (bf16) read from first half of out row, then the
// full f32 row is written in-place after the barrier.
struct Taps { float f[8]; };

__global__ __launch_bounds__(256) void k_filter(const unsigned short* __restrict__ ybuf,
    float* __restrict__ out, Taps tp) {
  int ch = blockIdx.x;
  int t = threadIdx.x;
  __shared__ float ysb[2336];   // phys(i) = i + (i>>3); logical j = y[j-8]
  const unsigned short* yc = ybuf + (size_t)ch * 4096;
  uint4 v = *(const uint4*)(yc + 8 * t);
  unsigned int wsv[4] = {v.x, v.y, v.z, v.w};
  int phys0 = 9 * t + 9;        // logical 8t+8
  #pragma unroll
  for (int p = 0; p < 4; ++p) {
    ysb[phys0 + 2 * p]     = bf2f((unsigned short)(wsv[p] & 0xffffu));
    ysb[phys0 + 2 * p + 1] = bf2f((unsigned short)(wsv[p] >> 16));
  }
  if (t < 8) ysb[t] = 0.f;                       // logical 0..7 (phys==logical)
  if (t >= 240 && t < 255) {
    int j = 2056 + (t - 240);                    // logical 2056..2070
    ysb[j + (j >> 3)] = 0.f;
  }
  __syncthreads();
  float r[22];
  int jb = 8 * t + 1;
  #pragma unroll
  for (int u = 0; u < 22; ++u) { int j = jb + u; r[u] = ysb[j + (j >> 3)]; }
  int m0 = 8 * t;
  float ao[15];
  #pragma unroll
  for (int vv = 0; vv < 15; ++vv) {
    int t4 = m0 - 4 + vv;
    float u = 0.f;
    #pragma unroll
    for (int p = 0; p < 8; ++p) u += tp.f[p] * r[vv + p];
    float a = (u >= 0.f ? u : 0.1f * u) * 1.41421356237309515f;
    ao[vv] = ((unsigned)t4 < 2048u) ? a : 0.f;
  }
  float res[8];
  #pragma unroll
  for (int w = 0; w < 8; ++w) {
    float yv = r[w + 7];
    float s = 0.35355339059327379f * (yv >= 0.f ? yv : 0.1f * yv);
    #pragma unroll
    for (int q = 0; q < 8; ++q) s += tp.f[q] * ao[w + q];
    res[w] = s;
  }
  float4 o0; o0.x = res[0]; o0.y = res[1]; o0.z = res[2]; o0.w = res[3];
  float4 o1; o1.x = res[4]; o1.y = res[5]; o1.z = res[6]; o1.w = res[7];
  float* orow = out + (size_t)ch * 2048 + m0;
  *(float4*)orow = o0;
  *((float4*)orow + 1) = o1;
}

// ------------------------------- host side -----------------------------------
static double bessel_i0(double x) {
  double s = 1.0, term = 1.0;
  for (int m = 1; m < 30; ++m) {
    double h = x * 0.5 / (double)m;
    term *= h * h;
    s += term;
  }
  return s;
}

extern "C" void kernel_launch(void* const* d_in, const int* in_sizes, int n_in,
                              void* d_out, int out_size, void* d_ws, size_t ws_size,
                              hipStream_t stream) {
  (void)in_sizes; (void)n_in; (void)out_size; (void)ws_size;
  const float* x  = (const float*)d_in[0];
  const float* w  = (const float*)d_in[1];
  const float* aw = (const float*)d_in[2];
  const float* ab = (const float*)d_in[3];
  const float* cw = (const float*)d_in[4];
  const float* cb = (const float*)d_in[5];
  const float* ne = (const float*)d_in[6];
  float* out = (float*)d_out;
  char* ws = (char*)d_ws;

  float* ssum = (float*)(ws + 0);
  float* cond = (float*)(ws + 4096);
  float* coef = (float*)(ws + 36864);
  float* rinv = (float*)(ws + 69632);
  unsigned short* wpack = (unsigned short*)(ws + 73728);   // 3,145,728 B
  float* W2 = (float*)(ws + 3219456);                      // 1,048,576 B
  unsigned short* xsT = (unsigned short*)(ws + 4268032);   // 33,587,200 B

  hipMemsetAsync(ssum, 0, 4, stream);
  k_cond<<<128, 256, 0, stream>>>(w, aw, ab, cond, ssum);
  k_wprep<<<512, 256, 0, stream>>>(cw, W2, rinv, wpack);
  k_dcoef<<<dim3(16, 16), 256, 0, stream>>>(W2, cond, rinv, ssum, coef);
  k_xprep<<<dim3(32, 8, 16), 256, 0, stream>>>(x, cond, ssum, ne, xsT);
  k_main<<<dim3(16, 4, 16), 256, 0, stream>>>(xsT, wpack, coef, cb, (unsigned short*)d_out);

  Taps tp;
  {
    double beta = 2.5;
    double i0b = bessel_i0(beta);
    for (int p = 0; p < 8; ++p) {
      int j = 2 * p + 1;          // odd tap index in 0..16
      int n = j - 8;              // -7..7 odd
      double f = sin(0.5 * M_PI * (double)n) / (M_PI * (double)n + 1e-8);
      double rr = (double)(j - 8) / 8.0;
      double win = bessel_i0(beta * sqrt(1.0 - rr * rr)) / i0b;
      tp.f[p] = (float)(win * f);
    }
  }
  k_filter<<<8192, 256, 0, stream>>>((const unsigned short*)d_out, out, tp);
}